// Round 6
// baseline (615.454 us; speedup 1.0000x reference)
//
#include <hip/hip_runtime.h>
#include <hip/hip_fp16.h>
#include <stdint.h>

// InstantNGP hash-grid embedding, round 9 (= round-8 resubmit; infra flake).
// Evidence (r3->r6): time tracks divergent-VMEM INSTRUCTION count, not L2
// request count or residency (FETCH swung +-130MB with zero time delta;
// window-merge trick with same instr count was exactly neutral; cutting
// instrs 160->112/pt gave 309->263us). => issue/TA-bound, latency hidden.
// Attack: fuse all 16 levels into one thread.
//   - x read once (3 loads) instead of 16x (48)
//   - dense 0..7 cell-major (2 loads/level; L2-thrash proven time-neutral)
//   - hash 8..15 plain 8 gathers (window trick dropped: neutral, costs VALU)
//   - fp32 out written DIRECTLY (8 nontemporal 16B stores) -> tmp buffer
//     (128MB traffic) and the whole transpose kernel eliminated.
// VMEM instrs/pt: 116 + transpose-kernel -> ~91 total.

#define N_LEVELS   16
#define LOG2_T     19
#define TABLE_SIZE (1u << LOG2_T)
#define HASH_MASK  (TABLE_SIZE - 1u)
#define P1 2654435761u
#define P2 805459861u
#define N_DENSE    8          // levels 0..7: dense cell-major restage

typedef float  fx4 __attribute__((ext_vector_type(4)));   // clang-native vec4

__constant__ int   c_res[N_DENSE]   = {16, 20, 25, 32, 40, 50, 64, 80};
// cell-major grids: R^3 cells, 32B (8 half2 corners) each; offsets in cells
__constant__ uint32_t c_coff[N_DENSE] = {0, 4096, 12096, 27721,
                                         60489, 124489, 249489, 511633};
#define CELL_TOTAL 1023633u   // *32B = 32.76MB

// compile-time copies for the fully-unrolled fused kernel (fold to literals)
constexpr int      kRes[N_LEVELS]   = {16, 20, 25, 32, 40, 50, 64, 80,
                                       101, 128, 161, 203, 256, 322, 406, 512};
constexpr float    kScale[N_LEVELS] = {8.0f, 10.0f, 12.5f, 16.0f, 20.0f, 25.0f,
                                       32.0f, 40.0f, 50.5f, 64.0f, 80.5f, 101.5f,
                                       128.0f, 161.0f, 203.0f, 256.0f};
constexpr uint32_t kCoff[N_DENSE]   = {0, 4096, 12096, 27721,
                                       60489, 124489, 249489, 511633};

// ---------------- pass 0a: fp16-convert hash tables (levels 8..15) ---------
__global__ __launch_bounds__(256) void conv_hash(
    const float2* __restrict__ emb, uint32_t* __restrict__ ht, int total)
{
    int i = blockIdx.x * 256 + threadIdx.x;
    if (i >= total) return;
    float2 v = emb[(size_t)N_DENSE * TABLE_SIZE + i];   // levels 8..15 contiguous
    __half2 h = __float22half2_rn(v);
    ht[i] = *(uint32_t*)&h;
}

// ---------------- pass 0b: cell-major fp16 grids (levels 0..7) -------------
__global__ __launch_bounds__(256) void conv_cell(
    const float2* __restrict__ emb, uint4* __restrict__ cg)
{
    int l = blockIdx.y;
    uint32_t c = blockIdx.x * 256 + threadIdx.x;
    uint32_t R = (uint32_t)c_res[l];
    if (c >= R * R * R) return;
    uint32_t ix = c % R;
    uint32_t r  = c / R;
    uint32_t iy = r % R;
    uint32_t iz = r / R;

    const float2* __restrict__ tb = emb + (size_t)l * TABLE_SIZE;
    uint32_t a0 = ix,      a1 = ix + 1u;     // prime[0]==1
    uint32_t b0 = iy * P1, b1 = b0 + P1;
    uint32_t d0 = iz * P2, d1 = d0 + P2;

    float2 f0 = tb[(a0 ^ b0 ^ d0) & HASH_MASK];
    float2 f1 = tb[(a1 ^ b0 ^ d0) & HASH_MASK];
    float2 f2 = tb[(a0 ^ b1 ^ d0) & HASH_MASK];
    float2 f3 = tb[(a1 ^ b1 ^ d0) & HASH_MASK];
    float2 f4 = tb[(a0 ^ b0 ^ d1) & HASH_MASK];
    float2 f5 = tb[(a1 ^ b0 ^ d1) & HASH_MASK];
    float2 f6 = tb[(a0 ^ b1 ^ d1) & HASH_MASK];
    float2 f7 = tb[(a1 ^ b1 ^ d1) & HASH_MASK];

    __half2 h0 = __float22half2_rn(f0), h1 = __float22half2_rn(f1);
    __half2 h2 = __float22half2_rn(f2), h3 = __float22half2_rn(f3);
    __half2 h4 = __float22half2_rn(f4), h5 = __float22half2_rn(f5);
    __half2 h6 = __float22half2_rn(f6), h7 = __float22half2_rn(f7);

    uint32_t base = 2u * (c_coff[l] + c);
    cg[base]      = make_uint4(*(uint32_t*)&h0, *(uint32_t*)&h1,
                               *(uint32_t*)&h2, *(uint32_t*)&h3);
    cg[base + 1u] = make_uint4(*(uint32_t*)&h4, *(uint32_t*)&h5,
                               *(uint32_t*)&h6, *(uint32_t*)&h7);
}

// ---------------- fused gather: 1 thread = 1 point, all 16 levels ----------
__global__ __launch_bounds__(256) void gather_all(
    const float* __restrict__ x,
    const uint32_t* __restrict__ ht,
    const uint4*    __restrict__ cg,
    float*          __restrict__ out, int npts)
{
    int b = blockIdx.x * 256 + threadIdx.x;
    if (b >= npts) return;

    size_t xb = (size_t)b * 3;
    float xx = x[xb], xy = x[xb + 1], xz = x[xb + 2];

    float e0 = 0.0f, e1 = 0.0f;               // stash for even level

    #pragma unroll
    for (int l = 0; l < N_LEVELS; ++l) {
        const float scale = kScale[l];
        const float hiv   = (float)kRes[l] - 1.0f;

        float rx = (xx + 1.0f) * scale;
        float ry = (xy + 1.0f) * scale;
        float rz = (xz + 1.0f) * scale;

        float fx = fminf(fmaxf(floorf(rx), 0.0f), hiv);
        float fy = fminf(fmaxf(floorf(ry), 0.0f), hiv);
        float fz = fminf(fmaxf(floorf(rz), 0.0f), hiv);

        float wx = rx - fx, wy = ry - fy, wz = rz - fz;
        uint32_t ix = (uint32_t)fx, iy = (uint32_t)fy, iz = (uint32_t)fz;

        uint32_t u0, u1, u2, u3, u4, u5, u6, u7;
        if (l < N_DENSE) {                    // cell-major: 2 loads, 1 line
            const uint32_t R    = (uint32_t)kRes[l];
            const uint32_t cidx = (iz * R + iy) * R + ix;
            const uint32_t base = 2u * (kCoff[l] + cidx);
            uint4 lo = cg[base];
            uint4 hi = cg[base + 1u];
            u0 = lo.x; u1 = lo.y; u2 = lo.z; u3 = lo.w;
            u4 = hi.x; u5 = hi.y; u6 = hi.z; u7 = hi.w;
        } else {                              // plain hash: 8 gathers
            const uint32_t* __restrict__ tb =
                ht + (size_t)(l - N_DENSE) * TABLE_SIZE;
            uint32_t a0 = ix,      a1 = ix + 1u;   // prime[0]==1
            uint32_t b0 = iy * P1, b1 = b0 + P1;
            uint32_t c0 = iz * P2, c1 = c0 + P2;
            u0 = tb[(a0 ^ b0 ^ c0) & HASH_MASK];
            u1 = tb[(a1 ^ b0 ^ c0) & HASH_MASK];
            u2 = tb[(a0 ^ b1 ^ c0) & HASH_MASK];
            u3 = tb[(a1 ^ b1 ^ c0) & HASH_MASK];
            u4 = tb[(a0 ^ b0 ^ c1) & HASH_MASK];
            u5 = tb[(a1 ^ b0 ^ c1) & HASH_MASK];
            u6 = tb[(a0 ^ b1 ^ c1) & HASH_MASK];
            u7 = tb[(a1 ^ b1 ^ c1) & HASH_MASK];
        }

        float2 v0 = __half22float2(*(__half2*)&u0);
        float2 v1 = __half22float2(*(__half2*)&u1);
        float2 v2 = __half22float2(*(__half2*)&u2);
        float2 v3 = __half22float2(*(__half2*)&u3);
        float2 v4 = __half22float2(*(__half2*)&u4);
        float2 v5 = __half22float2(*(__half2*)&u5);
        float2 v6 = __half22float2(*(__half2*)&u6);
        float2 v7 = __half22float2(*(__half2*)&u7);

        float ux = 1.0f - wx, uy = 1.0f - wy, uz = 1.0f - wz;
        float w0 = ux * uy * uz, w1 = wx * uy * uz;
        float w2 = ux * wy * uz, w3 = wx * wy * uz;
        float w4 = ux * uy * wz, w5 = wx * uy * wz;
        float w6 = ux * wy * wz, w7 = wx * wy * wz;

        float o0 = w0 * v0.x + w1 * v1.x + w2 * v2.x + w3 * v3.x
                 + w4 * v4.x + w5 * v5.x + w6 * v6.x + w7 * v7.x;
        float o1 = w0 * v0.y + w1 * v1.y + w2 * v2.y + w3 * v3.y
                 + w4 * v4.y + w5 * v5.y + w6 * v6.y + w7 * v7.y;

        // fp16 round-trip to keep numerics identical to prior (passing) rounds
        __half2 hr = __float22half2_rn(make_float2(o0, o1));
        float2 fr = __half22float2(hr);

        if (l & 1) {
            fx4 v; v.x = e0; v.y = e1; v.z = fr.x; v.w = fr.y;
            __builtin_nontemporal_store(
                v, (fx4*)(out + (size_t)b * 32 + (l >> 1) * 4));
        } else {
            e0 = fr.x; e1 = fr.y;
        }
    }
}

// ---------------- fallback (no workspace): direct fp32, point-major --------
__global__ __launch_bounds__(256) void hash_embed_direct(
    const float* __restrict__ x, const float* __restrict__ emb,
    float2* __restrict__ out, int npts)
{
    int t = blockIdx.x * 256 + threadIdx.x;
    int l = t & 15, b = t >> 4;
    if (b >= npts) return;
    size_t xb = (size_t)b * 3;
    constexpr float kS[16] = {8.0f, 10.0f, 12.5f, 16.0f, 20.0f, 25.0f,
                              32.0f, 40.0f, 50.5f, 64.0f, 80.5f, 101.5f,
                              128.0f, 161.0f, 203.0f, 256.0f};
    constexpr int   kR[16] = {16, 20, 25, 32, 40, 50, 64, 80,
                              101, 128, 161, 203, 256, 322, 406, 512};
    float scale = kS[l], hiv = (float)kR[l] - 1.0f;
    float rx = (x[xb] + 1.0f) * scale, ry = (x[xb+1] + 1.0f) * scale, rz = (x[xb+2] + 1.0f) * scale;
    float fx = fminf(fmaxf(floorf(rx), 0.0f), hiv);
    float fy = fminf(fmaxf(floorf(ry), 0.0f), hiv);
    float fz = fminf(fmaxf(floorf(rz), 0.0f), hiv);
    float wx = rx - fx, wy = ry - fy, wz = rz - fz;
    uint32_t ix = (uint32_t)fx, iy = (uint32_t)fy, iz = (uint32_t)fz;
    uint32_t a0 = ix, a1 = ix + 1u, b0 = iy * P1, b1 = b0 + P1, c0 = iz * P2, c1 = c0 + P2;
    const float2* tb = (const float2*)emb + (size_t)l * TABLE_SIZE;
    float2 v0 = tb[(a0^b0^c0)&HASH_MASK], v1 = tb[(a1^b0^c0)&HASH_MASK];
    float2 v2 = tb[(a0^b1^c0)&HASH_MASK], v3 = tb[(a1^b1^c0)&HASH_MASK];
    float2 v4 = tb[(a0^b0^c1)&HASH_MASK], v5 = tb[(a1^b0^c1)&HASH_MASK];
    float2 v6 = tb[(a0^b1^c1)&HASH_MASK], v7 = tb[(a1^b1^c1)&HASH_MASK];
    float ux = 1.0f - wx, uy = 1.0f - wy, uz = 1.0f - wz;
    float w0 = ux*uy*uz, w1 = wx*uy*uz, w2 = ux*wy*uz, w3 = wx*wy*uz;
    float w4 = ux*uy*wz, w5 = wx*uy*wz, w6 = ux*wy*wz, w7 = wx*wy*wz;
    float o0 = w0*v0.x+w1*v1.x+w2*v2.x+w3*v3.x+w4*v4.x+w5*v5.x+w6*v6.x+w7*v7.x;
    float o1 = w0*v0.y+w1*v1.y+w2*v2.y+w3*v3.y+w4*v4.y+w5*v5.y+w6*v6.y+w7*v7.y;
    out[(size_t)b * N_LEVELS + l] = make_float2(o0, o1);
}

extern "C" void kernel_launch(void* const* d_in, const int* in_sizes, int n_in,
                              void* d_out, int out_size, void* d_ws, size_t ws_size,
                              hipStream_t stream)
{
    const float*  x   = (const float*)d_in[0];
    const float2* emb = (const float2*)d_in[1];
    int npts = in_sizes[0] / 3;

    size_t ht_bytes = (size_t)N_DENSE * TABLE_SIZE * 4;   // 16.78MB fp16 tables
    size_t cg_bytes = (size_t)CELL_TOTAL * 32;            // 32.76MB cell grids
    int ht_total = N_DENSE * TABLE_SIZE;                  // 4.19M entries

    if (ws_size >= ht_bytes + cg_bytes) {                 // preferred (49.5MB)
        uint32_t* ht = (uint32_t*)d_ws;
        uint4*    cg = (uint4*)((char*)d_ws + ht_bytes);

        hipLaunchKernelGGL(conv_hash, dim3((ht_total + 255) / 256), dim3(256),
                           0, stream, emb, ht, ht_total);
        hipLaunchKernelGGL(conv_cell, dim3(2000, N_DENSE), dim3(256),
                           0, stream, emb, cg);
        hipLaunchKernelGGL(gather_all, dim3((npts + 255) / 256), dim3(256),
                           0, stream, x, ht, cg, (float*)d_out, npts);
    } else {                                              // no workspace
        int total = npts * N_LEVELS;
        hipLaunchKernelGGL(hash_embed_direct, dim3((total + 255) / 256), dim3(256),
                           0, stream, (const float*)x, (const float*)emb,
                           (float2*)d_out, npts);
    }
}

// Round 7
// 486.024 us; speedup vs baseline: 1.2663x; 1.2663x over previous
//
#include <hip/hip_runtime.h>
#include <hip/hip_fp16.h>
#include <stdint.h>

// InstantNGP hash-grid embedding, round 10.
// r9 fusion refuted: FETCH 266MB->1.31GB, 455us. Phasing IS the mechanism
// keeping the hot table inside the 4MiB/XCD L2; fused waves drift and the
// ~50MB combined set thrashes at a ~3TB/s L2-miss BW roofline.
// Refined model: time ~= 1 cy per VMEM instr per CU while L2-hit
// (r3:192instr->309us, r4/r6:~148->263us), misses have their own roofline.
// Attack (keep r6 phased structure, cut instrs with zero residency risk):
//   (a) x padded to float4 (staging pass): 3 -> 1 load/pt/phase (48->16)
//   (b) drop sel4 window-merge (proven neutral): plain 8 hash gathers
// Instrs/pt 148 -> 116 => predict gather ~206us, total ~400us.

#define N_LEVELS   16
#define LOG2_T     19
#define TABLE_SIZE (1u << LOG2_T)
#define HASH_MASK  (TABLE_SIZE - 1u)
#define P1 2654435761u
#define P2 805459861u
#define N_CELL     6          // levels 0..5: cell-major
#define N_DENSE    8          // levels 0..7 dense-staged overall

__constant__ int   c_res[N_LEVELS]   = {16, 20, 25, 32, 40, 50, 64, 80,
                                        101, 128, 161, 203, 256, 322, 406, 512};
// scale = res/2 (exact fp32); rel=(x+1)*scale matches ref to <=1 ulp.
__constant__ float c_scale[N_LEVELS] = {8.0f, 10.0f, 12.5f, 16.0f, 20.0f, 25.0f,
                                        32.0f, 40.0f, 50.5f, 64.0f, 80.5f, 101.5f,
                                        128.0f, 161.0f, 203.0f, 256.0f};

// ---- cell-major (levels 0..5): R^3 cells, 32B (8 half2) each --------------
__constant__ uint32_t c_coff[N_CELL] = {0, 4096, 12096, 27721, 60489, 124489};
#define CELL_TOTAL 249489u    // cells, *32B = 7.98MB

// ---- pair-major (levels 6..7): [S][S][R] entries, 8B = (v(ix),v(ix+1)) ----
__constant__ uint32_t c_poff[2] = {0, 270400};   // level6: 65*65*64
#define PAIR_TOTAL 795280u    // + level7: 81*81*80; *8B = 6.36MB

// ---------------- pass 0a: fp16-convert hash tables (levels 8..15) ---------
__global__ __launch_bounds__(256) void conv_hash(
    const float2* __restrict__ emb, uint32_t* __restrict__ ht, int total)
{
    int i = blockIdx.x * 256 + threadIdx.x;
    if (i >= total) return;
    float2 v = emb[(size_t)N_DENSE * TABLE_SIZE + i];   // levels 8..15 contiguous
    __half2 h = __float22half2_rn(v);
    ht[i] = *(uint32_t*)&h;
}

// ---------------- pass 0b: cell-major fp16 grids (levels 0..5) -------------
__global__ __launch_bounds__(256) void conv_cell(
    const float2* __restrict__ emb, uint4* __restrict__ cg)
{
    int l = blockIdx.y;
    uint32_t c = blockIdx.x * 256 + threadIdx.x;
    uint32_t R = (uint32_t)c_res[l];
    if (c >= R * R * R) return;
    uint32_t ix = c % R;
    uint32_t r  = c / R;
    uint32_t iy = r % R;
    uint32_t iz = r / R;

    const float2* __restrict__ tb = emb + (size_t)l * TABLE_SIZE;
    uint32_t a0 = ix,      a1 = ix + 1u;     // prime[0]==1
    uint32_t b0 = iy * P1, b1 = b0 + P1;
    uint32_t d0 = iz * P2, d1 = d0 + P2;

    float2 f0 = tb[(a0 ^ b0 ^ d0) & HASH_MASK];
    float2 f1 = tb[(a1 ^ b0 ^ d0) & HASH_MASK];
    float2 f2 = tb[(a0 ^ b1 ^ d0) & HASH_MASK];
    float2 f3 = tb[(a1 ^ b1 ^ d0) & HASH_MASK];
    float2 f4 = tb[(a0 ^ b0 ^ d1) & HASH_MASK];
    float2 f5 = tb[(a1 ^ b0 ^ d1) & HASH_MASK];
    float2 f6 = tb[(a0 ^ b1 ^ d1) & HASH_MASK];
    float2 f7 = tb[(a1 ^ b1 ^ d1) & HASH_MASK];

    __half2 h0 = __float22half2_rn(f0), h1 = __float22half2_rn(f1);
    __half2 h2 = __float22half2_rn(f2), h3 = __float22half2_rn(f3);
    __half2 h4 = __float22half2_rn(f4), h5 = __float22half2_rn(f5);
    __half2 h6 = __float22half2_rn(f6), h7 = __float22half2_rn(f7);

    uint32_t base = 2u * (c_coff[l] + c);
    cg[base]      = make_uint4(*(uint32_t*)&h0, *(uint32_t*)&h1,
                               *(uint32_t*)&h2, *(uint32_t*)&h3);
    cg[base + 1u] = make_uint4(*(uint32_t*)&h4, *(uint32_t*)&h5,
                               *(uint32_t*)&h6, *(uint32_t*)&h7);
}

// ---------------- pass 0c: pair-major fp16 grids (levels 6..7) -------------
__global__ __launch_bounds__(256) void conv_pair(
    const float2* __restrict__ emb, uint2* __restrict__ pp)
{
    int li = blockIdx.y;                       // 0 -> level 6, 1 -> level 7
    int l  = 6 + li;
    uint32_t e = blockIdx.x * 256 + threadIdx.x;
    uint32_t R = (uint32_t)c_res[l];
    uint32_t S = R + 1u;
    if (e >= R * S * S) return;
    uint32_t ix = e % R;
    uint32_t r  = e / R;
    uint32_t iy = r % S;
    uint32_t iz = r / S;
    const float2* __restrict__ tb = emb + (size_t)l * TABLE_SIZE;
    uint32_t hy = iy * P1, hz = iz * P2;
    uint32_t h0 = (ix        ^ hy ^ hz) & HASH_MASK;
    uint32_t h1 = ((ix + 1u) ^ hy ^ hz) & HASH_MASK;
    __half2 a = __float22half2_rn(tb[h0]);
    __half2 b = __float22half2_rn(tb[h1]);
    pp[c_poff[li] + e] = make_uint2(*(uint32_t*)&a, *(uint32_t*)&b);
}

// ---------------- pass 0d: pad x to float4 (1 dwordx4 load per pt-phase) ---
__global__ __launch_bounds__(256) void conv_x4(
    const float* __restrict__ x, float4* __restrict__ x4, int npts)
{
    int b = blockIdx.x * 256 + threadIdx.x;
    if (b >= npts) return;
    size_t xb = (size_t)b * 3;
    x4[b] = make_float4(x[xb], x[xb + 1], x[xb + 2], 0.0f);
}

// ---------------- gather core ----------------------------------------------
template <bool X4>
__device__ __forceinline__ void do_point(
    int l, int b, int npts,
    const float*  __restrict__ x,
    const float4* __restrict__ x4,
    const uint32_t* __restrict__ ht,
    const uint4*    __restrict__ cg,
    const uint2*    __restrict__ pp,
    uint32_t* __restrict__ tmp)
{
    if (b >= npts) return;
    float xx, xy, xz;
    if constexpr (X4) {
        float4 v = x4[b];
        xx = v.x; xy = v.y; xz = v.z;
    } else {
        size_t xb = (size_t)b * 3;
        xx = x[xb]; xy = x[xb + 1]; xz = x[xb + 2];
    }

    float scale = c_scale[l];
    float hiv   = (float)c_res[l] - 1.0f;

    float rx = (xx + 1.0f) * scale;
    float ry = (xy + 1.0f) * scale;
    float rz = (xz + 1.0f) * scale;

    float fx = fminf(fmaxf(floorf(rx), 0.0f), hiv);
    float fy = fminf(fmaxf(floorf(ry), 0.0f), hiv);
    float fz = fminf(fmaxf(floorf(rz), 0.0f), hiv);

    float wx = rx - fx, wy = ry - fy, wz = rz - fz;
    uint32_t ix = (uint32_t)fx, iy = (uint32_t)fy, iz = (uint32_t)fz;

    uint32_t u0, u1, u2, u3, u4, u5, u6, u7;
    if (l < N_CELL) {                         // cell-major: 2 loads, 1 line
        uint32_t R    = (uint32_t)c_res[l];
        uint32_t cidx = (iz * R + iy) * R + ix;
        uint32_t base = 2u * (c_coff[l] + cidx);
        uint4 lo = cg[base];
        uint4 hi = cg[base + 1u];
        u0 = lo.x; u1 = lo.y; u2 = lo.z; u3 = lo.w;
        u4 = hi.x; u5 = hi.y; u6 = hi.z; u7 = hi.w;
    } else if (l < N_DENSE) {                 // pair-major: 4 aligned dwordx2
        uint32_t R    = (uint32_t)c_res[l];
        uint32_t S    = R + 1u;
        uint32_t base = c_poff[l - N_CELL] + (iz * S + iy) * R + ix;
        uint32_t RS   = R * S;
        uint2 p0 = pp[base];
        uint2 p1 = pp[base + R];
        uint2 p2 = pp[base + RS];
        uint2 p3 = pp[base + RS + R];
        u0 = p0.x; u1 = p0.y; u2 = p1.x; u3 = p1.y;
        u4 = p2.x; u5 = p2.y; u6 = p3.x; u7 = p3.y;
    } else {                                  // plain hash: 8 gathers
        const uint32_t* __restrict__ tb = ht + (size_t)(l - N_DENSE) * TABLE_SIZE;
        uint32_t a0 = ix,      a1 = ix + 1u;  // prime[0]==1
        uint32_t b0 = iy * P1, b1 = b0 + P1;
        uint32_t c0 = iz * P2, c1 = c0 + P2;
        u0 = tb[(a0 ^ b0 ^ c0) & HASH_MASK];
        u1 = tb[(a1 ^ b0 ^ c0) & HASH_MASK];
        u2 = tb[(a0 ^ b1 ^ c0) & HASH_MASK];
        u3 = tb[(a1 ^ b1 ^ c0) & HASH_MASK];
        u4 = tb[(a0 ^ b0 ^ c1) & HASH_MASK];
        u5 = tb[(a1 ^ b0 ^ c1) & HASH_MASK];
        u6 = tb[(a0 ^ b1 ^ c1) & HASH_MASK];
        u7 = tb[(a1 ^ b1 ^ c1) & HASH_MASK];
    }

    float2 v0 = __half22float2(*(__half2*)&u0);
    float2 v1 = __half22float2(*(__half2*)&u1);
    float2 v2 = __half22float2(*(__half2*)&u2);
    float2 v3 = __half22float2(*(__half2*)&u3);
    float2 v4 = __half22float2(*(__half2*)&u4);
    float2 v5 = __half22float2(*(__half2*)&u5);
    float2 v6 = __half22float2(*(__half2*)&u6);
    float2 v7 = __half22float2(*(__half2*)&u7);

    float ux = 1.0f - wx, uy = 1.0f - wy, uz = 1.0f - wz;
    float w0 = ux * uy * uz, w1 = wx * uy * uz;
    float w2 = ux * wy * uz, w3 = wx * wy * uz;
    float w4 = ux * uy * wz, w5 = wx * uy * wz;
    float w6 = ux * wy * wz, w7 = wx * wy * wz;

    float o0 = w0 * v0.x + w1 * v1.x + w2 * v2.x + w3 * v3.x
             + w4 * v4.x + w5 * v5.x + w6 * v6.x + w7 * v7.x;
    float o1 = w0 * v0.y + w1 * v1.y + w2 * v2.y + w3 * v3.y
             + w4 * v4.y + w5 * v5.y + w6 * v6.y + w7 * v7.y;

    __half2 r = __float22half2_rn(make_float2(o0, o1));
    tmp[(size_t)l * npts + b] = *(uint32_t*)&r;
}

// grid.y = level (dispatch x-fastest -> level phases); 2 points/thread.
template <bool X4>
__global__ __launch_bounds__(256) void gather_lvl(
    const float*  __restrict__ x,
    const float4* __restrict__ x4,
    const uint32_t* __restrict__ ht,
    const uint4*    __restrict__ cg,
    const uint2*    __restrict__ pp,
    uint32_t* __restrict__ tmp, int npts)
{
    const int l  = blockIdx.y;
    const int bA = blockIdx.x * 512 + threadIdx.x;
    do_point<X4>(l, bA,       npts, x, x4, ht, cg, pp, tmp);
    do_point<X4>(l, bA + 256, npts, x, x4, ht, cg, pp, tmp);
}

// ---------------- pass 2: tmp[l][b] (half2) -> out[b][l] (float2) ----------
__global__ __launch_bounds__(256) void transpose_k(
    const uint32_t* __restrict__ tmp, float4* __restrict__ out4, int npts)
{
    __shared__ uint32_t sm[N_LEVELS][514];    // pad 2 -> <=2-way bank conflicts

    const int b0 = blockIdx.x * 512;
    const int t  = threadIdx.x;

    if (b0 + 512 <= npts) {
        #pragma unroll
        for (int l = 0; l < N_LEVELS; ++l) {
            uint2 u = *(const uint2*)&tmp[(size_t)l * npts + b0 + 2 * t];
            *(uint2*)&sm[l][2 * t] = u;       // single ds_write_b64
        }
        __syncthreads();
        #pragma unroll
        for (int k = 0; k < 16; ++k) {
            int q = k * 256 + t;              // float4 index in tile (0..4095)
            int p = q >> 3;                   // point in tile
            int j = q & 7;                    // float4 within point
            uint32_t a = sm[2 * j][p], b = sm[2 * j + 1][p];
            float2 f0 = __half22float2(*(__half2*)&a);
            float2 f1 = __half22float2(*(__half2*)&b);
            out4[(size_t)(b0 + p) * 8 + j] = make_float4(f0.x, f0.y, f1.x, f1.y);
        }
    } else {                                  // guarded tail tile
        for (int l = 0; l < N_LEVELS; ++l) {
            for (int s = 0; s < 2; ++s) {
                int b = b0 + 2 * t + s;
                if (b < npts) sm[l][2 * t + s] = tmp[(size_t)l * npts + b];
            }
        }
        __syncthreads();
        for (int k = 0; k < 16; ++k) {
            int q = k * 256 + t;
            int p = q >> 3, j = q & 7;
            if (b0 + p < npts) {
                uint32_t a = sm[2 * j][p], b = sm[2 * j + 1][p];
                float2 f0 = __half22float2(*(__half2*)&a);
                float2 f1 = __half22float2(*(__half2*)&b);
                out4[(size_t)(b0 + p) * 8 + j] = make_float4(f0.x, f0.y, f1.x, f1.y);
            }
        }
    }
}

// ---------------- fallback (no workspace): direct fp32, point-major --------
__global__ __launch_bounds__(256) void hash_embed_direct(
    const float* __restrict__ x, const float* __restrict__ emb,
    float2* __restrict__ out, int npts)
{
    int t = blockIdx.x * 256 + threadIdx.x;
    int l = t & 15, b = t >> 4;
    if (b >= npts) return;
    size_t xb = (size_t)b * 3;
    float scale = c_scale[l], hiv = (float)c_res[l] - 1.0f;
    float rx = (x[xb] + 1.0f) * scale, ry = (x[xb+1] + 1.0f) * scale, rz = (x[xb+2] + 1.0f) * scale;
    float fx = fminf(fmaxf(floorf(rx), 0.0f), hiv);
    float fy = fminf(fmaxf(floorf(ry), 0.0f), hiv);
    float fz = fminf(fmaxf(floorf(rz), 0.0f), hiv);
    float wx = rx - fx, wy = ry - fy, wz = rz - fz;
    uint32_t ix = (uint32_t)fx, iy = (uint32_t)fy, iz = (uint32_t)fz;
    uint32_t a0 = ix, a1 = ix + 1u, b0 = iy * P1, b1 = b0 + P1, c0 = iz * P2, c1 = c0 + P2;
    const float2* tb = (const float2*)emb + (size_t)l * TABLE_SIZE;
    float2 v0 = tb[(a0^b0^c0)&HASH_MASK], v1 = tb[(a1^b0^c0)&HASH_MASK];
    float2 v2 = tb[(a0^b1^c0)&HASH_MASK], v3 = tb[(a1^b1^c0)&HASH_MASK];
    float2 v4 = tb[(a0^b0^c1)&HASH_MASK], v5 = tb[(a1^b0^c1)&HASH_MASK];
    float2 v6 = tb[(a0^b1^c1)&HASH_MASK], v7 = tb[(a1^b1^c1)&HASH_MASK];
    float ux = 1.0f - wx, uy = 1.0f - wy, uz = 1.0f - wz;
    float w0 = ux*uy*uz, w1 = wx*uy*uz, w2 = ux*wy*uz, w3 = wx*wy*uz;
    float w4 = ux*uy*wz, w5 = wx*uy*wz, w6 = ux*wy*wz, w7 = wx*wy*wz;
    float o0 = w0*v0.x+w1*v1.x+w2*v2.x+w3*v3.x+w4*v4.x+w5*v5.x+w6*v6.x+w7*v7.x;
    float o1 = w0*v0.y+w1*v1.y+w2*v2.y+w3*v3.y+w4*v4.y+w5*v5.y+w6*v6.y+w7*v7.y;
    out[(size_t)b * N_LEVELS + l] = make_float2(o0, o1);
}

extern "C" void kernel_launch(void* const* d_in, const int* in_sizes, int n_in,
                              void* d_out, int out_size, void* d_ws, size_t ws_size,
                              hipStream_t stream)
{
    const float*  x   = (const float*)d_in[0];
    const float2* emb = (const float2*)d_in[1];
    int npts = in_sizes[0] / 3;

    size_t tmp_bytes = (size_t)npts * N_LEVELS * 4;        // half2 per (pt,lvl)
    size_t ht_bytes  = (size_t)N_DENSE * TABLE_SIZE * 4;   // 8 fp16 hash tables
    size_t cg_bytes  = (size_t)CELL_TOTAL * 32;            // cell grids 0..5
    size_t pp_bytes  = (size_t)PAIR_TOTAL * 8;             // pair grids 6..7
    size_t x4_bytes  = (size_t)npts * 16;                  // padded coords

    int ht_total = N_DENSE * TABLE_SIZE;                   // 4.19M entries
    size_t base_need = tmp_bytes + ht_bytes + cg_bytes + pp_bytes;

    if (ws_size >= base_need + x4_bytes) {                 // preferred (115MB)
        uint32_t* tmp = (uint32_t*)d_ws;
        uint32_t* ht  = (uint32_t*)((char*)d_ws + tmp_bytes);
        uint4*    cg  = (uint4*)   ((char*)d_ws + tmp_bytes + ht_bytes);
        uint2*    pp  = (uint2*)   ((char*)d_ws + tmp_bytes + ht_bytes + cg_bytes);
        float4*   x4  = (float4*)  ((char*)d_ws + base_need);

        hipLaunchKernelGGL(conv_hash, dim3((ht_total + 255) / 256), dim3(256),
                           0, stream, emb, ht, ht_total);
        hipLaunchKernelGGL(conv_cell, dim3(489, N_CELL), dim3(256),
                           0, stream, emb, cg);
        hipLaunchKernelGGL(conv_pair, dim3(2051, 2), dim3(256),
                           0, stream, emb, pp);
        hipLaunchKernelGGL(conv_x4, dim3((npts + 255) / 256), dim3(256),
                           0, stream, x, x4, npts);
        hipLaunchKernelGGL(HIP_KERNEL_NAME(gather_lvl<true>),
                           dim3((npts + 511) / 512, N_LEVELS), dim3(256),
                           0, stream, x, x4, ht, cg, pp, tmp, npts);
        hipLaunchKernelGGL(transpose_k, dim3((npts + 511) / 512), dim3(256),
                           0, stream, tmp, (float4*)d_out, npts);
    } else if (ws_size >= base_need) {                     // no-x4 tier (98MB)
        uint32_t* tmp = (uint32_t*)d_ws;
        uint32_t* ht  = (uint32_t*)((char*)d_ws + tmp_bytes);
        uint4*    cg  = (uint4*)   ((char*)d_ws + tmp_bytes + ht_bytes);
        uint2*    pp  = (uint2*)   ((char*)d_ws + tmp_bytes + ht_bytes + cg_bytes);

        hipLaunchKernelGGL(conv_hash, dim3((ht_total + 255) / 256), dim3(256),
                           0, stream, emb, ht, ht_total);
        hipLaunchKernelGGL(conv_cell, dim3(489, N_CELL), dim3(256),
                           0, stream, emb, cg);
        hipLaunchKernelGGL(conv_pair, dim3(2051, 2), dim3(256),
                           0, stream, emb, pp);
        hipLaunchKernelGGL(HIP_KERNEL_NAME(gather_lvl<false>),
                           dim3((npts + 511) / 512, N_LEVELS), dim3(256),
                           0, stream, x, (const float4*)nullptr, ht, cg, pp,
                           tmp, npts);
        hipLaunchKernelGGL(transpose_k, dim3((npts + 511) / 512), dim3(256),
                           0, stream, tmp, (float4*)d_out, npts);
    } else {                                               // no workspace
        int total = npts * N_LEVELS;
        hipLaunchKernelGGL(hash_embed_direct, dim3((total + 255) / 256), dim3(256),
                           0, stream, (const float*)x, (const float*)emb,
                           (float2*)d_out, npts);
    }
}

// Round 8
// 464.871 us; speedup vs baseline: 1.3239x; 1.0455x over previous
//
#include <hip/hip_runtime.h>
#include <hip/hip_fp16.h>
#include <stdint.h>

// InstantNGP hash-grid embedding, round 11.
// Model (r3-r10 evidence): divergent gathers cost TA cycles (~distinct
// 64B lines/wave-instr, ~1/cy/CU); coalesced loads cost only bytes.
// r10's x4 refuted instr-count law: -32 coalesced instrs but +33% x bytes
// -> +18us. r9: hash-table co-residency catastrophic (1.3GB FETCH).
// r4: DENSE co-residency thrash is time-neutral.
// Round 11: revert x4; merge all 8 dense levels into one y-slice (x read
// once for 8 levels, saves 21 coalesced loads/pt ~ 84MB L3 traffic;
// residency-safe per r4); hash stays 8 phases; 3 conv kernels -> 1 dispatch.

#define N_LEVELS   16
#define LOG2_T     19
#define TABLE_SIZE (1u << LOG2_T)
#define HASH_MASK  (TABLE_SIZE - 1u)
#define P1 2654435761u
#define P2 805459861u
#define N_CELL     6          // levels 0..5: cell-major
#define N_DENSE    8          // levels 0..7 dense-staged overall

// compile-time tables (fold to literals in unrolled dense loop)
constexpr int      kRes[N_LEVELS]   = {16, 20, 25, 32, 40, 50, 64, 80,
                                       101, 128, 161, 203, 256, 322, 406, 512};
// scale = res/2 (exact fp32); rel=(x+1)*scale matches ref to <=1 ulp.
constexpr float    kScale[N_LEVELS] = {8.0f, 10.0f, 12.5f, 16.0f, 20.0f, 25.0f,
                                       32.0f, 40.0f, 50.5f, 64.0f, 80.5f, 101.5f,
                                       128.0f, 161.0f, 203.0f, 256.0f};
// cell-major (levels 0..5): R^3 cells, 32B (8 half2) each; offsets in cells
constexpr uint32_t kCoff[N_CELL] = {0, 4096, 12096, 27721, 60489, 124489};
#define CELL_TOTAL 249489u    // cells, *32B = 7.98MB
// pair-major (levels 6..7): [S][S][R] entries, 8B = (v(ix),v(ix+1))
constexpr uint32_t kPoff[2] = {0, 270400};   // level6: 65*65*64
#define PAIR_TOTAL 795280u    // + level7: 81*81*80; *8B = 6.36MB

// ---------------- pass 0 (single dispatch): all table restaging ------------
// blocks [0,16384): fp16 hash tables; [16384,19318): cell grids 0..5;
// [19318,23420): pair grids 6..7.
#define HASH_BLKS 16384
#define CELL_BLKS 489         // per level, covers 50^3=125000
#define PAIR_BLKS 2051        // per level, covers 81*81*80=524880
#define CONV_GRID (HASH_BLKS + N_CELL * CELL_BLKS + 2 * PAIR_BLKS)   // 23420

__global__ __launch_bounds__(256) void conv_all(
    const float2* __restrict__ emb, uint32_t* __restrict__ ht,
    uint4* __restrict__ cg, uint2* __restrict__ pp)
{
    int blk = blockIdx.x;
    if (blk < HASH_BLKS) {                     // ---- fp16 hash levels 8..15
        int i = blk * 256 + (int)threadIdx.x;  // exactly 4.19M threads
        float2 v = emb[(size_t)N_DENSE * TABLE_SIZE + i];
        __half2 h = __float22half2_rn(v);
        ht[i] = *(uint32_t*)&h;
        return;
    }
    blk -= HASH_BLKS;
    if (blk < N_CELL * CELL_BLKS) {            // ---- cell grids levels 0..5
        int l = blk / CELL_BLKS;
        uint32_t c = (uint32_t)(blk % CELL_BLKS) * 256u + threadIdx.x;
        uint32_t R = (uint32_t)kRes[l];
        if (c >= R * R * R) return;
        uint32_t ix = c % R;
        uint32_t r  = c / R;
        uint32_t iy = r % R;
        uint32_t iz = r / R;
        const float2* __restrict__ tb = emb + (size_t)l * TABLE_SIZE;
        uint32_t a0 = ix,      a1 = ix + 1u;   // prime[0]==1
        uint32_t b0 = iy * P1, b1 = b0 + P1;
        uint32_t d0 = iz * P2, d1 = d0 + P2;
        float2 f0 = tb[(a0 ^ b0 ^ d0) & HASH_MASK];
        float2 f1 = tb[(a1 ^ b0 ^ d0) & HASH_MASK];
        float2 f2 = tb[(a0 ^ b1 ^ d0) & HASH_MASK];
        float2 f3 = tb[(a1 ^ b1 ^ d0) & HASH_MASK];
        float2 f4 = tb[(a0 ^ b0 ^ d1) & HASH_MASK];
        float2 f5 = tb[(a1 ^ b0 ^ d1) & HASH_MASK];
        float2 f6 = tb[(a0 ^ b1 ^ d1) & HASH_MASK];
        float2 f7 = tb[(a1 ^ b1 ^ d1) & HASH_MASK];
        __half2 h0 = __float22half2_rn(f0), h1 = __float22half2_rn(f1);
        __half2 h2 = __float22half2_rn(f2), h3 = __float22half2_rn(f3);
        __half2 h4 = __float22half2_rn(f4), h5 = __float22half2_rn(f5);
        __half2 h6 = __float22half2_rn(f6), h7 = __float22half2_rn(f7);
        uint32_t base = 2u * (kCoff[l] + c);
        cg[base]      = make_uint4(*(uint32_t*)&h0, *(uint32_t*)&h1,
                                   *(uint32_t*)&h2, *(uint32_t*)&h3);
        cg[base + 1u] = make_uint4(*(uint32_t*)&h4, *(uint32_t*)&h5,
                                   *(uint32_t*)&h6, *(uint32_t*)&h7);
        return;
    }
    blk -= N_CELL * CELL_BLKS;                 // ---- pair grids levels 6..7
    int li = blk / PAIR_BLKS;
    int l  = 6 + li;
    uint32_t e = (uint32_t)(blk % PAIR_BLKS) * 256u + threadIdx.x;
    uint32_t R = (uint32_t)kRes[l];
    uint32_t S = R + 1u;
    if (e >= R * S * S) return;
    uint32_t ix = e % R;
    uint32_t r  = e / R;
    uint32_t iy = r % S;
    uint32_t iz = r / S;
    const float2* __restrict__ tb = emb + (size_t)l * TABLE_SIZE;
    uint32_t hy = iy * P1, hz = iz * P2;
    uint32_t h0 = (ix        ^ hy ^ hz) & HASH_MASK;
    uint32_t h1 = ((ix + 1u) ^ hy ^ hz) & HASH_MASK;
    __half2 a = __float22half2_rn(tb[h0]);
    __half2 b = __float22half2_rn(tb[h1]);
    pp[kPoff[li] + e] = make_uint2(*(uint32_t*)&a, *(uint32_t*)&b);
}

// ---------------- gather core (coords passed in registers) -----------------
__device__ __forceinline__ void embed_one(
    int l, int b, int npts, float xx, float xy, float xz,
    const uint32_t* __restrict__ ht,
    const uint4*    __restrict__ cg,
    const uint2*    __restrict__ pp,
    uint32_t* __restrict__ tmp)
{
    float scale = kScale[l];
    float hiv   = (float)kRes[l] - 1.0f;

    float rx = (xx + 1.0f) * scale;
    float ry = (xy + 1.0f) * scale;
    float rz = (xz + 1.0f) * scale;

    float fx = fminf(fmaxf(floorf(rx), 0.0f), hiv);
    float fy = fminf(fmaxf(floorf(ry), 0.0f), hiv);
    float fz = fminf(fmaxf(floorf(rz), 0.0f), hiv);

    float wx = rx - fx, wy = ry - fy, wz = rz - fz;
    uint32_t ix = (uint32_t)fx, iy = (uint32_t)fy, iz = (uint32_t)fz;

    uint32_t u0, u1, u2, u3, u4, u5, u6, u7;
    if (l < N_CELL) {                         // cell-major: 2 loads, 1 line
        uint32_t R    = (uint32_t)kRes[l];
        uint32_t cidx = (iz * R + iy) * R + ix;
        uint32_t base = 2u * (kCoff[l] + cidx);
        uint4 lo = cg[base];
        uint4 hi = cg[base + 1u];
        u0 = lo.x; u1 = lo.y; u2 = lo.z; u3 = lo.w;
        u4 = hi.x; u5 = hi.y; u6 = hi.z; u7 = hi.w;
    } else if (l < N_DENSE) {                 // pair-major: 4 aligned dwordx2
        uint32_t R    = (uint32_t)kRes[l];
        uint32_t S    = R + 1u;
        uint32_t base = kPoff[l - N_CELL] + (iz * S + iy) * R + ix;
        uint32_t RS   = R * S;
        uint2 p0 = pp[base];
        uint2 p1 = pp[base + R];
        uint2 p2 = pp[base + RS];
        uint2 p3 = pp[base + RS + R];
        u0 = p0.x; u1 = p0.y; u2 = p1.x; u3 = p1.y;
        u4 = p2.x; u5 = p2.y; u6 = p3.x; u7 = p3.y;
    } else {                                  // plain hash: 8 gathers
        const uint32_t* __restrict__ tb = ht + (size_t)(l - N_DENSE) * TABLE_SIZE;
        uint32_t a0 = ix,      a1 = ix + 1u;  // prime[0]==1
        uint32_t b0 = iy * P1, b1 = b0 + P1;
        uint32_t c0 = iz * P2, c1 = c0 + P2;
        u0 = tb[(a0 ^ b0 ^ c0) & HASH_MASK];
        u1 = tb[(a1 ^ b0 ^ c0) & HASH_MASK];
        u2 = tb[(a0 ^ b1 ^ c0) & HASH_MASK];
        u3 = tb[(a1 ^ b1 ^ c0) & HASH_MASK];
        u4 = tb[(a0 ^ b0 ^ c1) & HASH_MASK];
        u5 = tb[(a1 ^ b0 ^ c1) & HASH_MASK];
        u6 = tb[(a0 ^ b1 ^ c1) & HASH_MASK];
        u7 = tb[(a1 ^ b1 ^ c1) & HASH_MASK];
    }

    float2 v0 = __half22float2(*(__half2*)&u0);
    float2 v1 = __half22float2(*(__half2*)&u1);
    float2 v2 = __half22float2(*(__half2*)&u2);
    float2 v3 = __half22float2(*(__half2*)&u3);
    float2 v4 = __half22float2(*(__half2*)&u4);
    float2 v5 = __half22float2(*(__half2*)&u5);
    float2 v6 = __half22float2(*(__half2*)&u6);
    float2 v7 = __half22float2(*(__half2*)&u7);

    float ux = 1.0f - wx, uy = 1.0f - wy, uz = 1.0f - wz;
    float w0 = ux * uy * uz, w1 = wx * uy * uz;
    float w2 = ux * wy * uz, w3 = wx * wy * uz;
    float w4 = ux * uy * wz, w5 = wx * uy * wz;
    float w6 = ux * wy * wz, w7 = wx * wy * wz;

    float o0 = w0 * v0.x + w1 * v1.x + w2 * v2.x + w3 * v3.x
             + w4 * v4.x + w5 * v5.x + w6 * v6.x + w7 * v7.x;
    float o1 = w0 * v0.y + w1 * v1.y + w2 * v2.y + w3 * v3.y
             + w4 * v4.y + w5 * v5.y + w6 * v6.y + w7 * v7.y;

    __half2 r = __float22half2_rn(make_float2(o0, o1));
    tmp[(size_t)l * npts + b] = *(uint32_t*)&r;
}

// grid.y in [0,9): y==0 -> all 8 dense levels (x read ONCE for 8 levels);
// y>=1 -> hash level 7+y (phased: one 2MB table hot per slice).
__global__ __launch_bounds__(256) void gather_lvl(
    const float* __restrict__ x,
    const uint32_t* __restrict__ ht,
    const uint4*    __restrict__ cg,
    const uint2*    __restrict__ pp,
    uint32_t* __restrict__ tmp, int npts)
{
    const int y  = blockIdx.y;
    const int bA = blockIdx.x * 512 + (int)threadIdx.x;
    const int bB = bA + 256;
    const bool vA = bA < npts, vB = bB < npts;

    float ax = 0.f, ay = 0.f, az = 0.f, bx = 0.f, by = 0.f, bz = 0.f;
    if (vA) { size_t p = (size_t)bA * 3; ax = x[p]; ay = x[p+1]; az = x[p+2]; }
    if (vB) { size_t p = (size_t)bB * 3; bx = x[p]; by = x[p+1]; bz = x[p+2]; }

    if (y == 0) {
        #pragma unroll
        for (int l = 0; l < N_DENSE; ++l) {
            if (vA) embed_one(l, bA, npts, ax, ay, az, ht, cg, pp, tmp);
            if (vB) embed_one(l, bB, npts, bx, by, bz, ht, cg, pp, tmp);
        }
    } else {
        const int l = 7 + y;
        if (vA) embed_one(l, bA, npts, ax, ay, az, ht, cg, pp, tmp);
        if (vB) embed_one(l, bB, npts, bx, by, bz, ht, cg, pp, tmp);
    }
}

// ---------------- pass 2: tmp[l][b] (half2) -> out[b][l] (float2) ----------
__global__ __launch_bounds__(256) void transpose_k(
    const uint32_t* __restrict__ tmp, float4* __restrict__ out4, int npts)
{
    __shared__ uint32_t sm[N_LEVELS][514];    // pad 2 -> <=2-way bank conflicts

    const int b0 = blockIdx.x * 512;
    const int t  = threadIdx.x;

    if (b0 + 512 <= npts) {
        #pragma unroll
        for (int l = 0; l < N_LEVELS; ++l) {
            uint2 u = *(const uint2*)&tmp[(size_t)l * npts + b0 + 2 * t];
            *(uint2*)&sm[l][2 * t] = u;       // single ds_write_b64
        }
        __syncthreads();
        #pragma unroll
        for (int k = 0; k < 16; ++k) {
            int q = k * 256 + t;              // float4 index in tile (0..4095)
            int p = q >> 3;                   // point in tile
            int j = q & 7;                    // float4 within point
            uint32_t a = sm[2 * j][p], b = sm[2 * j + 1][p];
            float2 f0 = __half22float2(*(__half2*)&a);
            float2 f1 = __half22float2(*(__half2*)&b);
            out4[(size_t)(b0 + p) * 8 + j] = make_float4(f0.x, f0.y, f1.x, f1.y);
        }
    } else {                                  // guarded tail tile
        for (int l = 0; l < N_LEVELS; ++l) {
            for (int s = 0; s < 2; ++s) {
                int b = b0 + 2 * t + s;
                if (b < npts) sm[l][2 * t + s] = tmp[(size_t)l * npts + b];
            }
        }
        __syncthreads();
        for (int k = 0; k < 16; ++k) {
            int q = k * 256 + t;
            int p = q >> 3, j = q & 7;
            if (b0 + p < npts) {
                uint32_t a = sm[2 * j][p], b = sm[2 * j + 1][p];
                float2 f0 = __half22float2(*(__half2*)&a);
                float2 f1 = __half22float2(*(__half2*)&b);
                out4[(size_t)(b0 + p) * 8 + j] = make_float4(f0.x, f0.y, f1.x, f1.y);
            }
        }
    }
}

// ---------------- fallback (no workspace): direct fp32, point-major --------
__global__ __launch_bounds__(256) void hash_embed_direct(
    const float* __restrict__ x, const float* __restrict__ emb,
    float2* __restrict__ out, int npts)
{
    int t = blockIdx.x * 256 + threadIdx.x;
    int l = t & 15, b = t >> 4;
    if (b >= npts) return;
    size_t xb = (size_t)b * 3;
    float scale = kScale[l], hiv = (float)kRes[l] - 1.0f;
    float rx = (x[xb] + 1.0f) * scale, ry = (x[xb+1] + 1.0f) * scale, rz = (x[xb+2] + 1.0f) * scale;
    float fx = fminf(fmaxf(floorf(rx), 0.0f), hiv);
    float fy = fminf(fmaxf(floorf(ry), 0.0f), hiv);
    float fz = fminf(fmaxf(floorf(rz), 0.0f), hiv);
    float wx = rx - fx, wy = ry - fy, wz = rz - fz;
    uint32_t ix = (uint32_t)fx, iy = (uint32_t)fy, iz = (uint32_t)fz;
    uint32_t a0 = ix, a1 = ix + 1u, b0 = iy * P1, b1 = b0 + P1, c0 = iz * P2, c1 = c0 + P2;
    const float2* tb = (const float2*)emb + (size_t)l * TABLE_SIZE;
    float2 v0 = tb[(a0^b0^c0)&HASH_MASK], v1 = tb[(a1^b0^c0)&HASH_MASK];
    float2 v2 = tb[(a0^b1^c0)&HASH_MASK], v3 = tb[(a1^b1^c0)&HASH_MASK];
    float2 v4 = tb[(a0^b0^c1)&HASH_MASK], v5 = tb[(a1^b0^c1)&HASH_MASK];
    float2 v6 = tb[(a0^b1^c1)&HASH_MASK], v7 = tb[(a1^b1^c1)&HASH_MASK];
    float ux = 1.0f - wx, uy = 1.0f - wy, uz = 1.0f - wz;
    float w0 = ux*uy*uz, w1 = wx*uy*uz, w2 = ux*wy*uz, w3 = wx*wy*uz;
    float w4 = ux*uy*wz, w5 = wx*uy*wz, w6 = ux*wy*wz, w7 = wx*wy*wz;
    float o0 = w0*v0.x+w1*v1.x+w2*v2.x+w3*v3.x+w4*v4.x+w5*v5.x+w6*v6.x+w7*v7.x;
    float o1 = w0*v0.y+w1*v1.y+w2*v2.y+w3*v3.y+w4*v4.y+w5*v5.y+w6*v6.y+w7*v7.y;
    out[(size_t)b * N_LEVELS + l] = make_float2(o0, o1);
}

extern "C" void kernel_launch(void* const* d_in, const int* in_sizes, int n_in,
                              void* d_out, int out_size, void* d_ws, size_t ws_size,
                              hipStream_t stream)
{
    const float*  x   = (const float*)d_in[0];
    const float2* emb = (const float2*)d_in[1];
    int npts = in_sizes[0] / 3;

    size_t tmp_bytes = (size_t)npts * N_LEVELS * 4;        // half2 per (pt,lvl)
    size_t ht_bytes  = (size_t)N_DENSE * TABLE_SIZE * 4;   // 8 fp16 hash tables
    size_t cg_bytes  = (size_t)CELL_TOTAL * 32;            // cell grids 0..5
    size_t pp_bytes  = (size_t)PAIR_TOTAL * 8;             // pair grids 6..7
    size_t need      = tmp_bytes + ht_bytes + cg_bytes + pp_bytes;   // 95.1MB

    if (ws_size >= need) {
        uint32_t* tmp = (uint32_t*)d_ws;
        uint32_t* ht  = (uint32_t*)((char*)d_ws + tmp_bytes);
        uint4*    cg  = (uint4*)   ((char*)d_ws + tmp_bytes + ht_bytes);
        uint2*    pp  = (uint2*)   ((char*)d_ws + tmp_bytes + ht_bytes + cg_bytes);

        hipLaunchKernelGGL(conv_all, dim3(CONV_GRID), dim3(256),
                           0, stream, emb, ht, cg, pp);
        hipLaunchKernelGGL(gather_lvl, dim3((npts + 511) / 512, 9), dim3(256),
                           0, stream, x, ht, cg, pp, tmp, npts);
        hipLaunchKernelGGL(transpose_k, dim3((npts + 511) / 512), dim3(256),
                           0, stream, tmp, (float4*)d_out, npts);
    } else {                                               // no workspace
        int total = npts * N_LEVELS;
        hipLaunchKernelGGL(hash_embed_direct, dim3((total + 255) / 256), dim3(256),
                           0, stream, (const float*)x, (const float*)emb,
                           (float2*)d_out, npts);
    }
}